// Round 9
// baseline (188.476 us; speedup 1.0000x reference)
//
#include <hip/hip_runtime.h>
#include <hip/hip_bf16.h>

// Problem constants
#define B_ 4
#define N_ 4096
#define D_ 1024
#define H_ 16
#define INNER_ 1024
#define M_ (B_ * N_)   // 16384 rows
#define CH_ 128        // scan chunks
#define CL_ 32         // chunk length = N_/CH_

using bf16x8 = __attribute__((ext_vector_type(8))) __bf16;
using f32x4  = __attribute__((ext_vector_type(4))) float;

__device__ __forceinline__ float bf2f(unsigned short v) {
  return __uint_as_float(((unsigned)v) << 16);
}
__device__ __forceinline__ unsigned short f2bf(float f) {
  __hip_bfloat16 h = __float2bfloat16(f);
  return *reinterpret_cast<unsigned short*>(&h);
}
__device__ __forceinline__ float sigm(float x) { return 1.f / (1.f + expf(-x)); }

__device__ __forceinline__ void gload_lds16(const void* g, void* l) {
  __builtin_amdgcn_global_load_lds(
      (const __attribute__((address_space(1))) unsigned int*)g,
      (__attribute__((address_space(3))) unsigned int*)l, 16, 0, 0);
}

// ---------------- fused weight-cast + LayerNorm (one launch) ----------------
#define W4_ ((INNER_ * D_) / 4)
__global__ __launch_bounds__(256) void lncast_kernel(
    const float* __restrict__ x, const float* __restrict__ gamma,
    const float* __restrict__ beta, __hip_bfloat16* __restrict__ xn,
    const float* __restrict__ wa, const float* __restrict__ wb,
    __hip_bfloat16* __restrict__ oa, __hip_bfloat16* __restrict__ ob) {
  if (blockIdx.x < 2048) {
    int i = blockIdx.x * 256 + threadIdx.x;
    const float* src = (i < W4_) ? wa : wb;
    __hip_bfloat16* dst = (i < W4_) ? oa : ob;
    int j = (i < W4_) ? i : i - W4_;
    float4 v = reinterpret_cast<const float4*>(src)[j];
    ushort4 o;
    o.x = f2bf(v.x); o.y = f2bf(v.y); o.z = f2bf(v.z); o.w = f2bf(v.w);
    reinterpret_cast<ushort4*>(dst)[j] = o;
    return;
  }
  const long row = blockIdx.x - 2048;
  const int t = threadIdx.x;
  const float4 v = reinterpret_cast<const float4*>(x + row * D_)[t];
  float s = v.x + v.y + v.z + v.w;
  float s2 = v.x * v.x + v.y * v.y + v.z * v.z + v.w * v.w;
#pragma unroll
  for (int o = 32; o > 0; o >>= 1) {
    s += __shfl_down(s, o);
    s2 += __shfl_down(s2, o);
  }
  __shared__ float red[8];
  const int lane = t & 63, wv = t >> 6;
  if (lane == 0) { red[wv] = s; red[4 + wv] = s2; }
  __syncthreads();
  const float sum = red[0] + red[1] + red[2] + red[3];
  const float sum2 = red[4] + red[5] + red[6] + red[7];
  const float mu = sum * (1.f / D_);
  const float var = sum2 * (1.f / D_) - mu * mu;
  const float rs = rsqrtf(var + 1e-5f);
  const float4 g = reinterpret_cast<const float4*>(gamma)[t];
  const float4 bb = reinterpret_cast<const float4*>(beta)[t];
  ushort4 o;
  o.x = f2bf((v.x - mu) * rs * g.x + bb.x);
  o.y = f2bf((v.y - mu) * rs * g.y + bb.y);
  o.z = f2bf((v.z - mu) * rs * g.z + bb.z);
  o.w = f2bf((v.w - mu) * rs * g.w + bb.w);
  reinterpret_cast<ushort4*>(xn + row * D_)[t] = o;
}

// ---------------- 128x256 bf16 NT GEMM, ring-3, 2 blocks/CU ----------------
// C[m,n] = sum_k A[m,k]*Bt[n,k]. 8 waves (2M x 4N), per-wave C = 64x64 (4x4 frags).
// LDS ring: 3 slots x (A 8KB + B 16KB) = 72 KiB -> 2 blocks/CU (144 <= 160 KB).
// BK=32/tile, stage t+2 ahead (3 loads/tile), counted vmcnt(3) boundary, one barrier/tile.
// Swizzle (r1-verified, 0 conflicts): logical (row r, 16B chunk c) at slot byte
// (r>>1)*128 + ((((r&1)<<2)|c) ^ ((r>>1)&7))*16; pre-swizzled global source (rule #21).
// Grid 512 blocks = 2/CU: independent blocks cover each other's barrier drains + C tail.
// FUSE: GEMM1 epilogue emits scan-chunk finals from f32 acc (per-wave rows = 2 chunks).
__device__ __forceinline__ void stc(float* p, float v) { *p = v; }
__device__ __forceinline__ void stc(__hip_bfloat16* p, float v) { *p = __float2bfloat16(v); }

template <typename TOUT, int NT, bool FUSE>
__global__ __launch_bounds__(512, 4) void gemm128_kernel(
    const __hip_bfloat16* __restrict__ A, const __hip_bfloat16* __restrict__ Bt,
    TOUT* __restrict__ C, float* __restrict__ finals, const float* __restrict__ alpha,
    int M, int N, int K) {
  static_assert(NT >= 4, "ring needs >=4 tiles");
  __shared__ __align__(16) char lds[73728];   // 3 x 24576
  const int tid = threadIdx.x;
  const int lane = tid & 63;
  const int wave = tid >> 6;

  // XCD-aware bijective swizzle (grid is 4 x 128 = 512 blocks = 8 XCDs x 64)
  int wg = blockIdx.y * gridDim.x + blockIdx.x;
  wg = (wg & 7) * 64 + (wg >> 3);
  const int bx = wg & 3;   // gridDim.x == 4
  const int by = wg >> 2;  // 0..127
  const long bm = (long)by * 128;
  const long bn = (long)bx * 256;

  // ---- staging source (pre-swizzled global address, per-thread constant) ----
  const int u0  = (tid & 7) ^ ((tid >> 3) & 7);
  const int r0  = 2 * (tid >> 3) + (u0 >> 2);   // logical row 0..127
  const int ck0 = u0 & 3;                        // logical 16B k-chunk
  const __hip_bfloat16* sA  = A  + (bm + r0) * (long)K + ck0 * 8;
  const __hip_bfloat16* sB0 = Bt + (bn + r0) * (long)K + ck0 * 8;
  const __hip_bfloat16* sB1 = sB0 + 128l * K;
  const int wb16 = wave * 1024;                  // wave-uniform stage sub-base

  // ---- reader constants (swizzled ds_read addresses) ----
  const int wm = wave >> 2;   // 0..1 (64-row half)
  const int wn = wave & 3;    // 0..3 (64-col quarter)
  const int fr = lane & 15;
  const int ck = lane >> 4;   // 0..3 (k-chunk of the MFMA fragment)
  const int pos = (((fr & 1) << 2) | ck) ^ ((fr >> 1) & 7);
  const int rbase = (fr >> 1) * 128 + pos * 16;
  const int laneA = wm * 4096 + rbase;           // + i*1024 within A slot
  const int laneB = 8192 + wn * 4096 + rbase;    // + j*1024 within B slot

  f32x4 acc[4][4] = {};

  char* slot0 = (char*)lds;
  char* slot1 = (char*)lds + 24576;
  char* slot2 = (char*)lds + 49152;

#define STAGE(sl, kt) do {                                                \
    gload_lds16(sA  + (long)(kt) * 32, (sl) + wb16);                      \
    gload_lds16(sB0 + (long)(kt) * 32, (sl) + 8192 + wb16);               \
    gload_lds16(sB1 + (long)(kt) * 32, (sl) + 16384 + wb16); } while (0)

  // prologue: stage tiles 0,1 into slots 0,1; land tile 0 (vmcnt(3) leaves t1 in flight)
  STAGE(slot0, 0);
  STAGE(slot1, 1);
  asm volatile("s_waitcnt vmcnt(3)" ::: "memory");
  __builtin_amdgcn_s_barrier();
  asm volatile("" ::: "memory");

  char* cur = slot0;
  char* nxt = slot1;
  char* stg = slot2;
#pragma unroll 4
  for (int t = 0; t < NT; ++t) {
    bf16x8 av[4], bv[4];
#pragma unroll
    for (int j = 0; j < 4; ++j) bv[j] = *(const bf16x8*)(cur + laneB + j * 1024);
#pragma unroll
    for (int i = 0; i < 4; ++i) av[i] = *(const bf16x8*)(cur + laneA + i * 1024);
    if (t + 2 < NT) STAGE(stg, t + 2);
    __builtin_amdgcn_s_setprio(1);
#pragma unroll
    for (int i = 0; i < 4; ++i)
#pragma unroll
      for (int j = 0; j < 4; ++j)
        acc[i][j] = __builtin_amdgcn_mfma_f32_16x16x32_bf16(av[i], bv[j], acc[i][j], 0, 0, 0);
    __builtin_amdgcn_s_setprio(0);
    // boundary: counted drain — tile t+1 landed; tile t+2's 3 loads stay in flight
    if (t + 2 < NT)      asm volatile("s_waitcnt vmcnt(3)" ::: "memory");
    else if (t + 1 < NT) asm volatile("s_waitcnt vmcnt(0)" ::: "memory");
    if (t + 1 < NT) {
      __builtin_amdgcn_s_barrier();
      asm volatile("" ::: "memory");
    }
    char* tmp = cur; cur = nxt; nxt = stg; stg = tmp;
  }
#undef STAGE

  // epilogue: C/D layout (m89-verified): col = lane&15, row = (lane>>4)*4 + reg
  const int cr = ck * 4;
#pragma unroll
  for (int i = 0; i < 4; ++i)
#pragma unroll
    for (int j = 0; j < 4; ++j)
#pragma unroll
      for (int r = 0; r < 4; ++r) {
        const long row = bm + wm * 64 + i * 16 + cr + r;
        const long col = bn + wn * 64 + j * 16 + fr;
        stc(&C[row * (long)N + col], acc[i][j][r]);
      }

  if constexpr (FUSE) {
    // scan-chunk finals from f32 acc: finals[b][c][e] = a * sum_rc (1-a)^(31-rc) xi[rc][e].
    // Wave rows = 64 = 2 chunks of 32 (frag pairs i=2q,2q+1); rc = (i&1)*16 + cr + r.
    const int head = (int)((bn + wn * 64) >> 6);  // uniform per wave
    const float a = sigm(alpha[head]);
    const float lw = log2f(1.f - a);
    float wgt[2][4];
#pragma unroll
    for (int p = 0; p < 2; ++p)
#pragma unroll
      for (int r = 0; r < 4; ++r)
        wgt[p][r] = exp2f((float)(31 - (p * 16 + cr + r)) * lw);
#pragma unroll
    for (int q = 0; q < 2; ++q) {        // chunk within wave's 64 rows
#pragma unroll
      for (int cf = 0; cf < 4; ++cf) {
        float s = 0.f;
#pragma unroll
        for (int p = 0; p < 2; ++p)
#pragma unroll
          for (int r = 0; r < 4; ++r)
            s += wgt[p][r] * acc[q * 2 + p][cf][r];
        s += __shfl_xor(s, 16);
        s += __shfl_xor(s, 32);
        if (ck == 0) {
          const long row0 = bm + wm * 64 + q * 32;
          const long bb = row0 >> 12;          // batch
          const long cq = (row0 >> 5) & 127;   // chunk within batch
          const int e = (int)bn + wn * 64 + cf * 16 + fr;
          finals[(bb * CH_ + cq) * INNER_ + e] = a * s;
        }
      }
    }
  }
}

// ---------------- scan phase 2: carry sweep over chunks ----------------
__global__ __launch_bounds__(256) void scan_carry_kernel(
    const float* __restrict__ finals, float* __restrict__ carries,
    const float* __restrict__ alpha) {
  const int g = blockIdx.x * 256 + threadIdx.x;  // 0..B_*INNER_-1
  const int b = g >> 10;
  const int e = g & 1023;
  const float a = sigm(alpha[e >> 6]);
  const float dc = powf(1.f - a, (float)CL_);
  float carry = 0.f;
  for (int c = 0; c < CH_; ++c) {
    const long idx = ((long)b * CH_ + c) * INNER_ + e;
    carries[idx] = carry;
    carry = finals[idx] + dc * carry;
  }
}

// ---------------- scan phase 3: full EMA seeded by carry ----------------
__global__ __launch_bounds__(256) void scan_apply_kernel(
    const __hip_bfloat16* __restrict__ xi, __hip_bfloat16* __restrict__ y,
    const float* __restrict__ carries, const float* __restrict__ alpha) {
  const int e0 = threadIdx.x * 4;
  const int c = blockIdx.y;
  const int b = blockIdx.z;
  const float a = sigm(alpha[e0 >> 6]);
  const float om = 1.f - a;
  const float4 cr = *reinterpret_cast<const float4*>(
      &carries[((long)b * CH_ + c) * INNER_ + e0]);
  float y0 = cr.x, y1 = cr.y, y2 = cr.z, y3 = cr.w;
  long base = ((long)b * N_ + (long)c * CL_) * INNER_ + e0;
  for (int t = 0; t < CL_; ++t) {
    ushort4 u = *(const ushort4*)(xi + base);
    y0 = om * y0 + a * bf2f(u.x);
    y1 = om * y1 + a * bf2f(u.y);
    y2 = om * y2 + a * bf2f(u.z);
    y3 = om * y3 + a * bf2f(u.w);
    ushort4 o;
    o.x = f2bf(y0); o.y = f2bf(y1); o.z = f2bf(y2); o.w = f2bf(y3);
    *(ushort4*)(y + base) = o;
    base += INNER_;
  }
}

extern "C" void kernel_launch(void* const* d_in, const int* in_sizes, int n_in,
                              void* d_out, int out_size, void* d_ws, size_t ws_size,
                              hipStream_t stream) {
  const float* x     = (const float*)d_in[0];
  const float* gamma = (const float*)d_in[1];
  const float* beta  = (const float*)d_in[2];
  const float* alpha = (const float*)d_in[3];
  const float* w_in  = (const float*)d_in[4];
  const float* w_out = (const float*)d_in[5];
  float* out = (float*)d_out;
  char* ws = (char*)d_ws;

  // ws layout (40 MB total):
  __hip_bfloat16* xn = (__hip_bfloat16*)ws;                       // 32 MB (reused as y)
  __hip_bfloat16* wi = (__hip_bfloat16*)(ws + (32l << 20));       // 2 MB
  __hip_bfloat16* wo = (__hip_bfloat16*)(ws + (34l << 20));       // 2 MB
  float* finals      = (float*)(ws + (36l << 20));                // 2 MB
  float* carries     = (float*)(ws + (38l << 20));                // 2 MB
  // xi (bf16, 32 MB) lives in d_out's first half; consumed before GEMM2 writes d_out
  __hip_bfloat16* xi = (__hip_bfloat16*)d_out;

  lncast_kernel<<<2048 + M_, 256, 0, stream>>>(x, gamma, beta, xn, w_in, w_out, wi, wo);

  // xi[m,e] = sum_d xn[m,d] * w_in[e,d]; epilogue also emits chunk finals
  gemm128_kernel<__hip_bfloat16, 32, true>
      <<<dim3(INNER_ / 256, M_ / 128), 512, 0, stream>>>(xn, wi, xi, finals, alpha,
                                                         M_, INNER_, D_);

  __hip_bfloat16* y = xn;  // overwrite xn (consumed by GEMM1)
  scan_carry_kernel<<<(B_ * INNER_) / 256, 256, 0, stream>>>(finals, carries, alpha);
  scan_apply_kernel<<<dim3(1, CH_, B_), 256, 0, stream>>>(xi, y, carries, alpha);

  // out[m,d] = sum_e y[m,e] * w_out[d,e]
  gemm128_kernel<float, 32, false>
      <<<dim3(D_ / 256, M_ / 128), 512, 0, stream>>>(y, wo, out, nullptr, nullptr,
                                                     M_, D_, INNER_);
}

// Round 10
// 123.249 us; speedup vs baseline: 1.5292x; 1.5292x over previous
//
#include <hip/hip_runtime.h>
#include <hip/hip_bf16.h>

// Problem constants
#define B_ 4
#define N_ 4096
#define D_ 1024
#define H_ 16
#define INNER_ 1024
#define M_ (B_ * N_)   // 16384 rows
#define CH_ 128        // scan chunks
#define CL_ 32         // chunk length = N_/CH_

using bf16x8 = __attribute__((ext_vector_type(8))) __bf16;
using f32x4  = __attribute__((ext_vector_type(4))) float;

__device__ __forceinline__ float bf2f(unsigned short v) {
  return __uint_as_float(((unsigned)v) << 16);
}
__device__ __forceinline__ unsigned short f2bf(float f) {
  __hip_bfloat16 h = __float2bfloat16(f);
  return *reinterpret_cast<unsigned short*>(&h);
}
__device__ __forceinline__ float sigm(float x) { return 1.f / (1.f + expf(-x)); }

__device__ __forceinline__ void gload_lds16(const void* g, void* l) {
  __builtin_amdgcn_global_load_lds(
      (const __attribute__((address_space(1))) unsigned int*)g,
      (__attribute__((address_space(3))) unsigned int*)l, 16, 0, 0);
}

// ---------------- fused weight-cast + LayerNorm (one launch) ----------------
#define W4_ ((INNER_ * D_) / 4)
__global__ __launch_bounds__(256) void lncast_kernel(
    const float* __restrict__ x, const float* __restrict__ gamma,
    const float* __restrict__ beta, __hip_bfloat16* __restrict__ xn,
    const float* __restrict__ wa, const float* __restrict__ wb,
    __hip_bfloat16* __restrict__ oa, __hip_bfloat16* __restrict__ ob) {
  if (blockIdx.x < 2048) {
    int i = blockIdx.x * 256 + threadIdx.x;
    const float* src = (i < W4_) ? wa : wb;
    __hip_bfloat16* dst = (i < W4_) ? oa : ob;
    int j = (i < W4_) ? i : i - W4_;
    float4 v = reinterpret_cast<const float4*>(src)[j];
    ushort4 o;
    o.x = f2bf(v.x); o.y = f2bf(v.y); o.z = f2bf(v.z); o.w = f2bf(v.w);
    reinterpret_cast<ushort4*>(dst)[j] = o;
    return;
  }
  const long row = blockIdx.x - 2048;
  const int t = threadIdx.x;
  const float4 v = reinterpret_cast<const float4*>(x + row * D_)[t];
  float s = v.x + v.y + v.z + v.w;
  float s2 = v.x * v.x + v.y * v.y + v.z * v.z + v.w * v.w;
#pragma unroll
  for (int o = 32; o > 0; o >>= 1) {
    s += __shfl_down(s, o);
    s2 += __shfl_down(s2, o);
  }
  __shared__ float red[8];
  const int lane = t & 63, wv = t >> 6;
  if (lane == 0) { red[wv] = s; red[4 + wv] = s2; }
  __syncthreads();
  const float sum = red[0] + red[1] + red[2] + red[3];
  const float sum2 = red[4] + red[5] + red[6] + red[7];
  const float mu = sum * (1.f / D_);
  const float var = sum2 * (1.f / D_) - mu * mu;
  const float rs = rsqrtf(var + 1e-5f);
  const float4 g = reinterpret_cast<const float4*>(gamma)[t];
  const float4 bb = reinterpret_cast<const float4*>(beta)[t];
  ushort4 o;
  o.x = f2bf((v.x - mu) * rs * g.x + bb.x);
  o.y = f2bf((v.y - mu) * rs * g.y + bb.y);
  o.z = f2bf((v.z - mu) * rs * g.z + bb.z);
  o.w = f2bf((v.w - mu) * rs * g.w + bb.w);
  reinterpret_cast<ushort4*>(xn + row * D_)[t] = o;
}

// ---------------- 256x256 bf16 NT GEMM, counted-vmcnt 4-slot ring (r1/r8, best) ----------
// C[m,n] = sum_k A[m,k] * Bt[n,k].  8 waves (2M x 4N), per-wave C = 128x64.
// LDS ring: 4 slots x (A 16KB + B 16KB) = 128 KiB. BK=32 per tile.
// Measured: 39.4 us / 874 TF / 0 bank conflicts — at the verified plain-HIP K=1024
// ceiling (guide m248v2: full 8-phase stack at K=1024 = 848 TF). Do not re-schedule.
// FUSE adds a scan-finals epilogue (GEMM1 only).
__device__ __forceinline__ void stc(float* p, float v) { *p = v; }
__device__ __forceinline__ void stc(__hip_bfloat16* p, float v) { *p = __float2bfloat16(v); }

template <typename TOUT, int NT, bool FUSE>
__global__ __launch_bounds__(512, 2) void gemm256_kernel(
    const __hip_bfloat16* __restrict__ A, const __hip_bfloat16* __restrict__ Bt,
    TOUT* __restrict__ C, float* __restrict__ finals, const float* __restrict__ alpha,
    int M, int N, int K) {
  static_assert(NT >= 4, "ring needs >=4 tiles");
  __shared__ __align__(16) char lds[131072];
  const int tid = threadIdx.x;
  const int lane = tid & 63;
  const int wave = tid >> 6;

  // XCD-aware bijective swizzle (grid is 4 x 64 = 256 blocks = 8 XCDs x 32)
  int wg = blockIdx.y * gridDim.x + blockIdx.x;
  wg = (wg & 7) * 32 + (wg >> 3);
  const int bx = wg & 3;   // gridDim.x == 4
  const int by = wg >> 2;
  const long bm = (long)by * 256;
  const long bn = (long)bx * 256;

  // ---- staging source (pre-swizzled global address, per-thread constant) ----
  const int u0  = (tid & 7) ^ ((tid >> 3) & 7);
  const int r0  = 2 * (tid >> 3) + (u0 >> 2);   // logical row (round 0)
  const int ck0 = u0 & 3;                        // logical 16B k-chunk
  const __hip_bfloat16* sA0 = A  + (bm + r0) * (long)K + ck0 * 8;
  const __hip_bfloat16* sA1 = sA0 + 128l * K;
  const __hip_bfloat16* sB0 = Bt + (bn + r0) * (long)K + ck0 * 8;
  const __hip_bfloat16* sB1 = sB0 + 128l * K;
  char* dbase = (char*)lds + wave * 1024;        // wave-uniform LDS dest base

  // ---- reader constants (swizzled ds_read addresses) ----
  const int wm = wave >> 2;   // 0..1
  const int wn = wave & 3;    // 0..3
  const int fr = lane & 15;
  const int ck = lane >> 4;   // 0..3 (k-chunk of the MFMA fragment)
  const int pos = (((fr & 1) << 2) | ck) ^ ((fr >> 1) & 7);
  const int laneA = wm * 8192 + (fr >> 1) * 128 + pos * 16;
  const int laneB = 16384 + wn * 4096 + (fr >> 1) * 128 + pos * 16;

  f32x4 acc[8][4] = {};

#define STAGE_A(kt) do { const int _s = (kt) & 3;                         \
    gload_lds16(sA0 + (long)(kt) * 32, dbase + _s * 32768);               \
    gload_lds16(sA1 + (long)(kt) * 32, dbase + _s * 32768 + 8192); } while (0)
#define STAGE_B(kt) do { const int _s = (kt) & 3;                         \
    gload_lds16(sB0 + (long)(kt) * 32, dbase + _s * 32768 + 16384);       \
    gload_lds16(sB1 + (long)(kt) * 32, dbase + _s * 32768 + 24576); } while (0)

  // prologue: stage tiles 0 and 1, land tile 0 (vmcnt(4) leaves tile 1 in flight)
  STAGE_A(0); STAGE_B(0);
  STAGE_A(1); STAGE_B(1);
  asm volatile("s_waitcnt vmcnt(4)" ::: "memory");
  __builtin_amdgcn_s_barrier();
  asm volatile("" ::: "memory");

#pragma unroll 4
  for (int t = 0; t < NT; ++t) {
    const char* base = (const char*)lds + (t & 3) * 32768;
    bf16x8 bv[4], av[4];
#pragma unroll
    for (int c = 0; c < 4; ++c) bv[c] = *(const bf16x8*)(base + laneB + c * 1024);
#pragma unroll
    for (int r = 0; r < 4; ++r) av[r] = *(const bf16x8*)(base + laneA + r * 1024);
    if (t + 2 < NT) STAGE_A(t + 2);
    __builtin_amdgcn_s_setprio(1);
#pragma unroll
    for (int r = 0; r < 4; ++r)
#pragma unroll
      for (int c = 0; c < 4; ++c)
        acc[r][c] = __builtin_amdgcn_mfma_f32_16x16x32_bf16(av[r], bv[c], acc[r][c], 0, 0, 0);
    __builtin_amdgcn_s_setprio(0);
#pragma unroll
    for (int r = 0; r < 4; ++r) av[r] = *(const bf16x8*)(base + laneA + (r + 4) * 1024);
    if (t + 2 < NT) STAGE_B(t + 2);
    __builtin_amdgcn_s_setprio(1);
#pragma unroll
    for (int r = 0; r < 4; ++r)
#pragma unroll
      for (int c = 0; c < 4; ++c)
        acc[r + 4][c] = __builtin_amdgcn_mfma_f32_16x16x32_bf16(av[r], bv[c], acc[r + 4][c], 0, 0, 0);
    __builtin_amdgcn_s_setprio(0);
    // tile boundary: counted drain — everything except tile t+2's 4 loads landed
    if (t < NT - 3) asm volatile("s_waitcnt vmcnt(4)" ::: "memory");
    else            asm volatile("s_waitcnt vmcnt(0)" ::: "memory");
    __builtin_amdgcn_s_barrier();
    asm volatile("" ::: "memory");
  }
#undef STAGE_A
#undef STAGE_B

  // epilogue: C/D layout (m89-verified): col = lane&15, row = (lane>>4)*4 + reg
  const int cr = ck * 4;
#pragma unroll
  for (int rf = 0; rf < 8; ++rf)
#pragma unroll
    for (int cf = 0; cf < 4; ++cf)
#pragma unroll
      for (int r = 0; r < 4; ++r) {
        const long row = bm + wm * 128 + rf * 16 + cr + r;
        const long col = bn + wn * 64 + cf * 16 + fr;
        stc(&C[row * (long)N + col], acc[rf][cf][r]);
      }

  if constexpr (FUSE) {
    // scan-chunk finals from f32 acc: finals[b][c][e] = a * sum_rc (1-a)^(31-rc) xi[rc][e].
    // Wave rows = 4 chunks of 32 (rf pairs); rc = (rf&1)*16 + cr + r; head uniform per wave.
    const int head = (int)((bn + wn * 64) >> 6);
    const float a = sigm(alpha[head]);
    const float lw = log2f(1.f - a);
    float wgt[2][4];
#pragma unroll
    for (int p = 0; p < 2; ++p)
#pragma unroll
      for (int r = 0; r < 4; ++r)
        wgt[p][r] = exp2f((float)(31 - (p * 16 + cr + r)) * lw);
#pragma unroll
    for (int q = 0; q < 4; ++q) {        // chunk within wave's 128 rows
#pragma unroll
      for (int cf = 0; cf < 4; ++cf) {
        float s = 0.f;
#pragma unroll
        for (int p = 0; p < 2; ++p)
#pragma unroll
          for (int r = 0; r < 4; ++r)
            s += wgt[p][r] * acc[q * 2 + p][cf][r];
        s += __shfl_xor(s, 16);
        s += __shfl_xor(s, 32);
        if (ck == 0) {
          const long row0 = bm + wm * 128 + q * 32;
          const long bb = row0 >> 12;          // batch
          const long cq = (row0 >> 5) & 127;   // chunk within batch
          const int e = (int)bn + wn * 64 + cf * 16 + fr;
          finals[(bb * CH_ + cq) * INNER_ + e] = a * s;
        }
      }
    }
  }
}

// ---------------- scan phase 2: carry sweep over chunks ----------------
__global__ __launch_bounds__(256) void scan_carry_kernel(
    const float* __restrict__ finals, float* __restrict__ carries,
    const float* __restrict__ alpha) {
  const int g = blockIdx.x * 256 + threadIdx.x;  // 0..B_*INNER_-1
  const int b = g >> 10;
  const int e = g & 1023;
  const float a = sigm(alpha[e >> 6]);
  const float dc = powf(1.f - a, (float)CL_);
  float carry = 0.f;
  for (int c = 0; c < CH_; ++c) {
    const long idx = ((long)b * CH_ + c) * INNER_ + e;
    carries[idx] = carry;
    carry = finals[idx] + dc * carry;
  }
}

// ---------------- scan phase 3: full EMA seeded by carry ----------------
__global__ __launch_bounds__(256) void scan_apply_kernel(
    const __hip_bfloat16* __restrict__ xi, __hip_bfloat16* __restrict__ y,
    const float* __restrict__ carries, const float* __restrict__ alpha) {
  const int e0 = threadIdx.x * 4;
  const int c = blockIdx.y;
  const int b = blockIdx.z;
  const float a = sigm(alpha[e0 >> 6]);
  const float om = 1.f - a;
  const float4 cr = *reinterpret_cast<const float4*>(
      &carries[((long)b * CH_ + c) * INNER_ + e0]);
  float y0 = cr.x, y1 = cr.y, y2 = cr.z, y3 = cr.w;
  long base = ((long)b * N_ + (long)c * CL_) * INNER_ + e0;
  for (int t = 0; t < CL_; ++t) {
    ushort4 u = *(const ushort4*)(xi + base);
    y0 = om * y0 + a * bf2f(u.x);
    y1 = om * y1 + a * bf2f(u.y);
    y2 = om * y2 + a * bf2f(u.z);
    y3 = om * y3 + a * bf2f(u.w);
    ushort4 o;
    o.x = f2bf(y0); o.y = f2bf(y1); o.z = f2bf(y2); o.w = f2bf(y3);
    *(ushort4*)(y + base) = o;
    base += INNER_;
  }
}

extern "C" void kernel_launch(void* const* d_in, const int* in_sizes, int n_in,
                              void* d_out, int out_size, void* d_ws, size_t ws_size,
                              hipStream_t stream) {
  const float* x     = (const float*)d_in[0];
  const float* gamma = (const float*)d_in[1];
  const float* beta  = (const float*)d_in[2];
  const float* alpha = (const float*)d_in[3];
  const float* w_in  = (const float*)d_in[4];
  const float* w_out = (const float*)d_in[5];
  float* out = (float*)d_out;
  char* ws = (char*)d_ws;

  // ws layout (40 MB total):
  __hip_bfloat16* xn = (__hip_bfloat16*)ws;                       // 32 MB (reused as y)
  __hip_bfloat16* wi = (__hip_bfloat16*)(ws + (32l << 20));       // 2 MB
  __hip_bfloat16* wo = (__hip_bfloat16*)(ws + (34l << 20));       // 2 MB
  float* finals      = (float*)(ws + (36l << 20));                // 2 MB
  float* carries     = (float*)(ws + (38l << 20));                // 2 MB
  // xi (bf16, 32 MB) lives in d_out's first half; consumed before GEMM2 writes d_out
  __hip_bfloat16* xi = (__hip_bfloat16*)d_out;

  lncast_kernel<<<2048 + M_, 256, 0, stream>>>(x, gamma, beta, xn, w_in, w_out, wi, wo);

  // xi[m,e] = sum_d xn[m,d] * w_in[e,d]; epilogue also emits chunk finals
  gemm256_kernel<__hip_bfloat16, 32, true>
      <<<dim3(INNER_ / 256, M_ / 256), 512, 0, stream>>>(xn, wi, xi, finals, alpha,
                                                         M_, INNER_, D_);

  __hip_bfloat16* y = xn;  // overwrite xn (consumed by GEMM1)
  scan_carry_kernel<<<(B_ * INNER_) / 256, 256, 0, stream>>>(finals, carries, alpha);
  scan_apply_kernel<<<dim3(1, CH_, B_), 256, 0, stream>>>(xi, y, carries, alpha);

  // out[m,d] = sum_e y[m,e] * w_out[d,e]
  gemm256_kernel<float, 32, false>
      <<<dim3(D_ / 256, M_ / 256), 512, 0, stream>>>(y, wo, out, nullptr, nullptr,
                                                     M_, D_, INNER_);
}